// Round 12
// baseline (521.226 us; speedup 1.0000x reference)
//
#include <hip/hip_runtime.h>

typedef __bf16 v8bf  __attribute__((ext_vector_type(8)));
typedef float  v4f   __attribute__((ext_vector_type(4)));
typedef int    v4i   __attribute__((ext_vector_type(4)));
typedef float  f32x2 __attribute__((ext_vector_type(2)));
union FR { v4i i4; v8bf bf; };

static constexpr int BATCH = 131072;
static constexpr int SENSN = 61;
static constexpr int NSTEP = 10;
static constexpr int TPB   = 256;
static constexpr int ROWP  = 72;   // ushorts/row: 144 B stride = 36 dw = 4 mod 32 banks -> 2-way (free)

#define RCP(x)  __builtin_amdgcn_rcpf(x)

// function, not macro: braced-init args are fine
__device__ __forceinline__ f32x2 FMA2(f32x2 a, f32x2 b, f32x2 c) {
    return __builtin_elementwise_fma(a, b, c);   // -> v_pk_fma_f32
}

#define R32(M) \
  M(0) M(1) M(2) M(3) M(4) M(5) M(6) M(7) \
  M(8) M(9) M(10) M(11) M(12) M(13) M(14) M(15) \
  M(16) M(17) M(18) M(19) M(20) M(21) M(22) M(23) \
  M(24) M(25) M(26) M(27) M(28) M(29) M(30) M(31)

// pack two f32 -> dword of 2 bf16 (truncation): low16 = bf16(lo), hi16 = bf16(hi)
__device__ __forceinline__ unsigned pk(float hi, float lo) {
    return __builtin_amdgcn_perm(__float_as_uint(hi), __float_as_uint(lo), 0x07060302u);
}

// tanh for a pair, ONE v_rcp total. CF-5 rational + clamp:
// tanh(x) ~= x(945+105s+s^2)/(945+420s+15s^2), s=x^2; approx > tanh and
// exceeds 1 monotonically past ~3.9, so clamp to [-1,1] caps tail err at ~7e-4.
__device__ __forceinline__ f32x2 tanh2(f32x2 x) {
    const f32x2 c945 = {945.f, 945.f};
    const f32x2 c105 = {105.f, 105.f};
    const f32x2 c420 = {420.f, 420.f};
    const f32x2 c15  = {15.f, 15.f};
    const f32x2 one  = {1.f, 1.f};
    const f32x2 mone = {-1.f, -1.f};
    f32x2 s  = x * x;
    f32x2 n  = FMA2(s, s + c105, c945);
    f32x2 xn = x * n;
    f32x2 d  = FMA2(s, FMA2(s, c15, c420), c945);
    float R  = RCP(d.x * d.y);
    f32x2 R2 = { R, R };
    f32x2 t  = xn * (R2 * __builtin_shufflevector(d, d, 1, 0));
    t = __builtin_elementwise_min(t, one);
    t = __builtin_elementwise_max(t, mone);
    return t;
}
__device__ __forceinline__ float tanh1(float x) {
    float s = x * x;
    float n = fmaf(s, s + 105.f, 945.f);
    float d = fmaf(s, fmaf(s, 15.f, 420.f), 945.f);
    float t = x * n * RCP(d);
    return fminf(fmaxf(t, -1.f), 1.f);
}

__global__ void
__attribute__((amdgpu_flat_work_group_size(256, 256), amdgpu_waves_per_eu(2, 2)))
node_kernel(const float* __restrict__ pad0,
            const float* __restrict__ sens,
            const float* __restrict__ W1,
            const float* __restrict__ b1v,
            const float* __restrict__ W2,
            const float* __restrict__ b2v,
            const float* __restrict__ W3,
            const float* __restrict__ b3v,
            const float* __restrict__ scale_p,
            float* __restrict__ out)
{
    __shared__ ushort abuf[4 * 64 * ROWP];

    const int tid  = threadIdx.x;
    const int wv   = tid >> 6;
    const int lane = tid & 63;
    const int lo   = lane & 15;
    const int hh   = lane >> 4;
    const int hh0  = (lane >> 4) & 1;   // xor-16 bit
    const int hh1  = (lane >> 5) & 1;   // xor-32 bit
    const int b    = blockIdx.x * TPB + tid;

    ushort* __restrict__ aw = abuf + wv * 64 * ROWP;

    const float scale = scale_p[0];
    const float h     = 0.1f;

    // ---- one-time: W2 fragments, used as MFMA A-operand (computes zz^T) ----
    FR b2f[4][2];
#pragma unroll
    for (int jb = 0; jb < 4; ++jb)
#pragma unroll
        for (int kc = 0; kc < 2; ++kc) {
            float w[8];
#pragma unroll
            for (int i = 0; i < 8; ++i)
                w[i] = W2[(hh*8 + i + 32*kc)*64 + lo + 16*jb];
            b2f[jb][kc].i4 = (v4i){ (int)pk(w[1],w[0]), (int)pk(w[3],w[2]),
                                    (int)pk(w[5],w[4]), (int)pk(w[7],w[6]) };
        }
    // layer-3 weights per lane, n-paired for pk_fma: j = 16jb+4hh+q
    f32x2 W3n01[4][4];   // {W3[j][0], W3[j][1]}
    float W3n2s[4][4];   //  W3[j][2]
#pragma unroll
    for (int jb = 0; jb < 4; ++jb)
#pragma unroll
        for (int q = 0; q < 4; ++q) {
            const int j = 16*jb + 4*hh + q;
            W3n01[jb][q] = (f32x2){ W3[j*3 + 0], W3[j*3 + 1] };
            W3n2s[jb][q] = W3[j*3 + 2];
        }
    // layer-2 bias, q-paired (plain, no prescale)
    f32x2 b2lo[4], b2hi[4];
#pragma unroll
    for (int jb = 0; jb < 4; ++jb) {
        b2lo[jb] = (f32x2){ b2v[16*jb + 4*hh + 0], b2v[16*jb + 4*hh + 1] };
        b2hi[jb] = (f32x2){ b2v[16*jb + 4*hh + 2], b2v[16*jb + 4*hh + 3] };
    }
    const float b30 = b3v[0], b31 = b3v[1], b32 = b3v[2];

    const float* __restrict__ w1r0 = W1;          // row 0 (y0)
    const float* __restrict__ w1r1 = W1 + 64;     // row 1 (y1)
    const float* __restrict__ w1r2 = W1 + 128;    // row 2 (y2)
    const float* __restrict__ w1rt = W1 + 4096;   // row 64 (t)

    // ---- one-time: S' pairs = b1 + sensory @ W1[3:64] in named f32x2 VGPRs ----
#define SDECL(k) f32x2 s2_##k = *(const f32x2*)(b1v + 2*(k));
    R32(SDECL)
#undef SDECL
    {
        const float* __restrict__ srow = sens + (long)b * SENSN;
#pragma unroll 1
        for (int s = 0; s < SENSN; ++s) {
            const float xv = srow[s];
            const f32x2 xv2 = { xv, xv };
            const float* __restrict__ w = W1 + (3 + s) * 64;
#define SFMA(k) s2_##k = FMA2(xv2, *(const f32x2*)(w + 2*(k)), s2_##k);
            R32(SFMA)
#undef SFMA
        }
    }

    float y0 = pad0[b*3 + 0];
    float y1 = pad0[b*3 + 1];
    float y2 = pad0[b*3 + 2];

    float k00=0,k01=0,k02=0, k10=0,k11=0,k12=0, k20=0,k21=0,k22=0,
          k30=0,k31=0,k32=0, k40=0,k41=0,k42=0;

#pragma unroll 1
    for (int step = 0; step < NSTEP; ++step) {
        const float t0 = (float)step * h;
#pragma unroll 1
        for (int st = 0; st < 6; ++st) {
            // ---- phase A: dopri5 stage combine (wave-uniform switch) ----
            float tt = t0, v0 = y0, v1 = y1, v2 = y2;
            switch (st) {
            case 0: break;
            case 1: {
                const float a21 = 0.2f;
                v0 = fmaf(h, a21*k00, y0); v1 = fmaf(h, a21*k01, y1); v2 = fmaf(h, a21*k02, y2);
                tt = t0 + 0.2f*h;
            } break;
            case 2: {
                const float a31 = 3.f/40.f, a32 = 9.f/40.f;
                v0 = fmaf(h, a31*k00 + a32*k10, y0);
                v1 = fmaf(h, a31*k01 + a32*k11, y1);
                v2 = fmaf(h, a31*k02 + a32*k12, y2);
                tt = t0 + 0.3f*h;
            } break;
            case 3: {
                const float a41 = 44.f/45.f, a42 = -56.f/15.f, a43 = 32.f/9.f;
                v0 = fmaf(h, a41*k00 + a42*k10 + a43*k20, y0);
                v1 = fmaf(h, a41*k01 + a42*k11 + a43*k21, y1);
                v2 = fmaf(h, a41*k02 + a42*k12 + a43*k22, y2);
                tt = t0 + 0.8f*h;
            } break;
            case 4: {
                const float a51 = 19372.f/6561.f, a52 = -25360.f/2187.f,
                            a53 = 64448.f/6561.f, a54 = -212.f/729.f;
                v0 = fmaf(h, a51*k00 + a52*k10 + a53*k20 + a54*k30, y0);
                v1 = fmaf(h, a51*k01 + a52*k11 + a53*k21 + a54*k31, y1);
                v2 = fmaf(h, a51*k02 + a52*k12 + a53*k22 + a54*k32, y2);
                tt = t0 + (8.f/9.f)*h;
            } break;
            default: {
                const float a61 = 9017.f/3168.f, a62 = -355.f/33.f,
                            a63 = 46732.f/5247.f, a64 = 49.f/176.f, a65 = -5103.f/18656.f;
                v0 = fmaf(h, a61*k00 + a62*k10 + a63*k20 + a64*k30 + a65*k40, y0);
                v1 = fmaf(h, a61*k01 + a62*k11 + a63*k21 + a64*k31 + a65*k41, y1);
                v2 = fmaf(h, a61*k02 + a62*k12 + a63*k22 + a64*k32 + a65*k42, y2);
                tt = t0 + h;
            } break;
            }
            const f32x2 v0p2 = { v0, v0 }, v1p2 = { v1, v1 },
                        v2p2 = { v2, v2 }, ttp2 = { tt, tt };

            // ---- phase B: layer1 rank-4 (pk_fma) + rational tanh, stage bf16 ----
            unsigned pw[32];
#define L1P(k) { \
    f32x2 z2 = s2_##k; \
    z2 = FMA2(v0p2, *(const f32x2*)(w1r0 + 2*(k)), z2); \
    z2 = FMA2(v1p2, *(const f32x2*)(w1r1 + 2*(k)), z2); \
    z2 = FMA2(v2p2, *(const f32x2*)(w1r2 + 2*(k)), z2); \
    z2 = FMA2(ttp2, *(const f32x2*)(w1rt + 2*(k)), z2); \
    f32x2 t2 = tanh2(z2); \
    pw[k] = pk(t2.y, t2.x); }
            R32(L1P)
#undef L1P
            {
                v4i* __restrict__ dst = (v4i*)&aw[lane * ROWP];
#pragma unroll
                for (int w8 = 0; w8 < 8; ++w8)
                    dst[w8] = (v4i){ (int)pw[4*w8+0], (int)pw[4*w8+1],
                                     (int)pw[4*w8+2], (int)pw[4*w8+3] };
            }
            asm volatile("" ::: "memory");

            // ---- phases C/D/E fused per nb-block (acc live = 16 regs) ----
            const v4f z4 = {0.f, 0.f, 0.f, 0.f};
            f32x2 p01[4];            // accum for n=0,1
            float p2s[4];            // accum for n=2
#pragma unroll
            for (int nb = 0; nb < 4; ++nb) { p01[nb] = (f32x2){0.f, 0.f}; p2s[nb] = 0.f; }
#pragma unroll
            for (int nb = 0; nb < 4; ++nb) {
                FR a0, a1;
                a0.i4 = *(const v4i*)&aw[(lo + 16*nb)*ROWP + hh*8];
                a1.i4 = *(const v4i*)&aw[(lo + 16*nb)*ROWP + hh*8 + 32];
                v4f acc[4];
#pragma unroll
                for (int jb = 0; jb < 4; ++jb) {
                    v4f t = __builtin_amdgcn_mfma_f32_16x16x32_bf16(b2f[jb][0].bf, a0.bf, z4, 0, 0, 0);
                    acc[jb] = __builtin_amdgcn_mfma_f32_16x16x32_bf16(b2f[jb][1].bf, a1.bf, t, 0, 0, 0);
                }
#pragma unroll
                for (int jb = 0; jb < 4; ++jb) {
                    f32x2 zlo = __builtin_shufflevector(acc[jb], acc[jb], 0, 1) + b2lo[jb];
                    f32x2 zhi = __builtin_shufflevector(acc[jb], acc[jb], 2, 3) + b2hi[jb];
                    f32x2 tlo = tanh2(zlo);
                    f32x2 thi = tanh2(zhi);
                    float tq[4] = { tlo.x, tlo.y, thi.x, thi.y };
#pragma unroll
                    for (int q = 0; q < 4; ++q) {
                        const f32x2 ts = { tq[q], tq[q] };
                        p01[nb] = FMA2(ts, W3n01[jb][q], p01[nb]);
                        p2s[nb] = fmaf(tq[q], W3n2s[jb][q], p2s[nb]);
                    }
                }
            }
            asm volatile("" ::: "memory");

            float p[4][3];
#pragma unroll
            for (int nb = 0; nb < 4; ++nb) {
                p[nb][0] = p01[nb].x; p[nb][1] = p01[nb].y; p[nb][2] = p2s[nb];
            }

            // ---- reduce-scatter butterfly: lane d ends with o for batch row d ----
            float q2[2][3];
#pragma unroll
            for (int j2 = 0; j2 < 2; ++j2)
#pragma unroll
                for (int n = 0; n < 3; ++n) {
                    float keep = hh1 ? p[2+j2][n] : p[j2][n];
                    float send = hh1 ? p[j2][n]   : p[2+j2][n];
                    q2[j2][n] = keep + __shfl_xor(send, 32, 64);
                }
            float o0, o1, o2;
            {
                float keep0 = hh0 ? q2[1][0] : q2[0][0];
                float send0 = hh0 ? q2[0][0] : q2[1][0];
                o0 = keep0 + __shfl_xor(send0, 16, 64);
                float keep1 = hh0 ? q2[1][1] : q2[0][1];
                float send1 = hh0 ? q2[0][1] : q2[1][1];
                o1 = keep1 + __shfl_xor(send1, 16, 64);
                float keep2 = hh0 ? q2[1][2] : q2[0][2];
                float send2 = hh0 ? q2[0][2] : q2[1][2];
                o2 = keep2 + __shfl_xor(send2, 16, 64);
            }

            // ---- final tanh*scale, RK bookkeeping ----
            const float r0 = scale * tanh1(o0 + b30);
            const float r1 = scale * tanh1(o1 + b31);
            const float r2 = scale * tanh1(o2 + b32);

            switch (st) {
            case 0: k00=r0; k01=r1; k02=r2; break;
            case 1: k10=r0; k11=r1; k12=r2; break;
            case 2: k20=r0; k21=r1; k22=r2; break;
            case 3: k30=r0; k31=r1; k32=r2; break;
            case 4: k40=r0; k41=r1; k42=r2; break;
            default: {
                const float c1 = 35.f/384.f,  c3c = 500.f/1113.f,
                            c4 = 125.f/192.f, c5 = -2187.f/6784.f, c6 = 11.f/84.f;
                y0 = fmaf(h, c1*k00 + c3c*k20 + c4*k30 + c5*k40 + c6*r0, y0);
                y1 = fmaf(h, c1*k01 + c3c*k21 + c4*k31 + c5*k41 + c6*r1, y1);
                y2 = fmaf(h, c1*k02 + c3c*k22 + c4*k32 + c5*k42 + c6*r2, y2);
            } break;
            }
        }
    }

    out[b*3 + 0] = y0;
    out[b*3 + 1] = y1;
    out[b*3 + 2] = y2;
}

extern "C" void kernel_launch(void* const* d_in, const int* in_sizes, int n_in,
                              void* d_out, int out_size, void* d_ws, size_t ws_size,
                              hipStream_t stream) {
    const float* pad0 = (const float*)d_in[0];
    const float* sens = (const float*)d_in[1];
    const float* W1   = (const float*)d_in[2];
    const float* b1v  = (const float*)d_in[3];
    const float* W2   = (const float*)d_in[4];
    const float* b2v  = (const float*)d_in[5];
    const float* W3   = (const float*)d_in[6];
    const float* b3v  = (const float*)d_in[7];
    const float* sc   = (const float*)d_in[8];
    float* outp = (float*)d_out;

    dim3 grid(BATCH / TPB), block(TPB);
    hipLaunchKernelGGL(node_kernel, grid, block, 0, stream,
                       pad0, sens, W1, b1v, W2, b2v, W3, b3v, sc, outp);
}